// Round 3
// baseline (339.958 us; speedup 1.0000x reference)
//
#include <hip/hip_runtime.h>
#include <stdint.h>

typedef __attribute__((ext_vector_type(8))) short short8;
typedef __attribute__((ext_vector_type(4))) float floatx4;
typedef __attribute__((ext_vector_type(4))) unsigned short ushort4v;

#define B_SZ 2
#define T_SZ 2048
#define NH   16
#define HD   64
#define C_SZ 1024
#define M_SZ (B_SZ * T_SZ)   // 4096 tokens

static __device__ __forceinline__ unsigned short f2bf(float f) {
    union { float f; unsigned int u; } v; v.f = f;
    unsigned int r = v.u + 0x7fffu + ((v.u >> 16) & 1u);
    return (unsigned short)(r >> 16);
}
static __device__ __forceinline__ float bf2f(unsigned short u) {
    union { float f; unsigned int u; } v; v.u = ((unsigned int)u) << 16;
    return v.f;
}

// convert 8 consecutive floats at p (32B-aligned) to short8 of bf16
static __device__ __forceinline__ short8 ld8_f32_to_bf16(const float* p) {
    float4 f0 = *(const float4*)p;
    float4 f1 = *(const float4*)(p + 4);
    short8 s;
    s[0] = (short)f2bf(f0.x); s[1] = (short)f2bf(f0.y);
    s[2] = (short)f2bf(f0.z); s[3] = (short)f2bf(f0.w);
    s[4] = (short)f2bf(f1.x); s[5] = (short)f2bf(f1.y);
    s[6] = (short)f2bf(f1.z); s[7] = (short)f2bf(f1.w);
    return s;
}

// ---------------------------------------------------------------------------
// NT GEMM: C[m,n] = sum_k A[m,k] * W[n,k]   (M=4096, N=K=1024)
// 128x128 tile, BK=32, 256 threads = 2x2 waves, 4x4 16x16x32 bf16 MFMAs/wave.
// Inputs fp32 (converted to bf16 during LDS staging), accumulate fp32.
// MODE 0 (QKV): grid.z selects {Wq,Wk,Wv}; fused epilogues:
//   z=0: RoPE + RMSNorm + 0.125*log2e  -> qh (B,H,T,D) bf16
//   z=1: RoPE + RMSNorm                -> kh (B,H,T,D) bf16
//   z=2: transpose                     -> vt (B,H,D,T) bf16
// MODE 1 (out-proj): A is bf16 (yb); writes fp32 (B,T,C) to Cf = d_out.
// ---------------------------------------------------------------------------
template <int MODE>
__global__ __launch_bounds__(256)
void gemm_nt(const float* __restrict__ Af,
             const unsigned short* __restrict__ Ab,
             const float* __restrict__ W0,
             const float* __restrict__ W1,
             const float* __restrict__ W2,
             const float* __restrict__ cosp,
             const float* __restrict__ sinp,
             unsigned short* __restrict__ qh,
             unsigned short* __restrict__ kh,
             unsigned short* __restrict__ vt,
             float* __restrict__ Cf)
{
    constexpr int K = C_SZ;
    constexpr int LDST = 40;  // 32 + 8 pad; row stride 80 B (16B-aligned)
    __shared__ __align__(16) unsigned short As[128 * LDST];
    __shared__ __align__(16) unsigned short Bs[128 * LDST];

    const int tid  = threadIdx.x;
    const int wave = tid >> 6, lane = tid & 63;
    const int wm = wave >> 1, wn = wave & 1;
    const int quad = lane >> 4, l16 = lane & 15;
    const int mb = blockIdx.x * 128, nb = blockIdx.y * 128;
    const int z  = blockIdx.z;

    const float* Wp = (MODE == 0) ? (z == 0 ? W0 : (z == 1 ? W1 : W2)) : W0;

    floatx4 acc[4][4] = {};

    const int arow = tid >> 2;          // 0..63 (+64 on 2nd chunk)
    const int acol = (tid & 3) * 8;     // 0,8,16,24

    for (int k0 = 0; k0 < K; k0 += 32) {
        __syncthreads();
        #pragma unroll
        for (int i = 0; i < 2; ++i) {
            int row = arow + i * 64;
            if (MODE == 0) {
                *(short8*)&As[row * LDST + acol] =
                    ld8_f32_to_bf16(&Af[(size_t)(mb + row) * K + k0 + acol]);
            } else {
                *(short8*)&As[row * LDST + acol] =
                    *(const short8*)&Ab[(size_t)(mb + row) * K + k0 + acol];
            }
            *(short8*)&Bs[row * LDST + acol] =
                ld8_f32_to_bf16(&Wp[(size_t)(nb + row) * K + k0 + acol]);
        }
        __syncthreads();

        short8 af[4], bfr[4];
        #pragma unroll
        for (int mt = 0; mt < 4; ++mt)
            af[mt] = *(const short8*)&As[(wm * 64 + mt * 16 + l16) * LDST + quad * 8];
        #pragma unroll
        for (int nt = 0; nt < 4; ++nt)
            bfr[nt] = *(const short8*)&Bs[(wn * 64 + nt * 16 + l16) * LDST + quad * 8];
        #pragma unroll
        for (int mt = 0; mt < 4; ++mt)
            #pragma unroll
            for (int nt = 0; nt < 4; ++nt)
                acc[mt][nt] = __builtin_amdgcn_mfma_f32_16x16x32_bf16(
                    af[mt], bfr[nt], acc[mt][nt], 0, 0, 0);
    }

    if (MODE == 1) {
        #pragma unroll
        for (int mt = 0; mt < 4; ++mt)
            #pragma unroll
            for (int nt = 0; nt < 4; ++nt)
                #pragma unroll
                for (int i = 0; i < 4; ++i) {
                    int row = mb + wm * 64 + mt * 16 + quad * 4 + i;
                    int col = nb + wn * 64 + nt * 16 + l16;
                    Cf[(size_t)row * C_SZ + col] = acc[mt][nt][i];
                }
        return;
    }

    // -------- fused QKV epilogues --------
    const int h = blockIdx.y * 2 + wn;   // head index (wave-uniform)

    if (z == 2) {
        // V: transpose-scatter to vt (B,H,D,T); 4 consecutive t per 8B store
        #pragma unroll
        for (int mt = 0; mt < 4; ++mt) {
            int gr0 = mb + wm * 64 + mt * 16 + quad * 4;  // token row of reg 0
            int b = gr0 >> 11, t0 = gr0 & (T_SZ - 1);
            #pragma unroll
            for (int nt = 0; nt < 4; ++nt) {
                int d = nt * 16 + l16;
                ushort4v pk;
                pk.x = f2bf(acc[mt][nt][0]);
                pk.y = f2bf(acc[mt][nt][1]);
                pk.z = f2bf(acc[mt][nt][2]);
                pk.w = f2bf(acc[mt][nt][3]);
                *(ushort4v*)&vt[((size_t)(b * NH + h) * HD + d) * T_SZ + t0] = pk;
            }
        }
        return;
    }

    // Q (z=0) / K (z=1): RoPE + RMSNorm (+ scale for Q), write (B,H,T,D)
    unsigned short* dst = (z == 0) ? qh : kh;
    const float qscale = (z == 0) ? (0.125f * 1.4426950408889634f) : 1.0f;
    const float eps = 1.1920929e-07f;   // finfo(float32).eps, per reference

    #pragma unroll
    for (int mt = 0; mt < 4; ++mt) {
        #pragma unroll
        for (int i = 0; i < 4; ++i) {
            int gr = mb + wm * 64 + mt * 16 + quad * 4 + i;
            int b = gr >> 11, t = gr & (T_SZ - 1);
            float ce = cosp[t * 32 + l16];
            float se = sinp[t * 32 + l16];
            float co = cosp[t * 32 + 16 + l16];
            float so = sinp[t * 32 + 16 + l16];
            float a0 = acc[mt][0][i], a1 = acc[mt][1][i];
            float a2 = acc[mt][2][i], a3 = acc[mt][3][i];
            // d = nt*16+l16; RoPE pairs (d, d+32) = (nt, nt+2), same lane
            float y0 = a0 * ce + a2 * se;
            float y1 = a1 * co + a3 * so;
            float y2 = a2 * ce - a0 * se;
            float y3 = a3 * co - a1 * so;
            float ss = y0 * y0 + y1 * y1 + y2 * y2 + y3 * y3;
            ss += __shfl_xor(ss, 1, 64);
            ss += __shfl_xor(ss, 2, 64);
            ss += __shfl_xor(ss, 4, 64);
            ss += __shfl_xor(ss, 8, 64);
            float rn = rsqrtf(ss * (1.0f / 64.0f) + eps) * qscale;
            size_t base = ((size_t)(b * NH + h) * T_SZ + t) * (size_t)HD;
            dst[base +  0 + l16] = f2bf(y0 * rn);
            dst[base + 16 + l16] = f2bf(y1 * rn);
            dst[base + 32 + l16] = f2bf(y2 * rn);
            dst[base + 48 + l16] = f2bf(y3 * rn);
        }
    }
}

// ---------------------------------------------------------------------------
// Flash attention (non-causal). Block = 4 waves = 64 queries of one (b,h).
// Wave w owns query rows w*16..w*16+15. Online softmax in log2 domain
// (scale folded into q̂). P goes C-layout -> LDS -> A-layout.
// ---------------------------------------------------------------------------
__global__ __launch_bounds__(256)
void attn(const unsigned short* __restrict__ qh,
          const unsigned short* __restrict__ kh,
          const unsigned short* __restrict__ vt,
          unsigned short* __restrict__ y)
{
    constexpr int LD = 72;  // 64 + 8 pad, rows 144 B (16B-aligned)
    __shared__ __align__(16) unsigned short Qs[64 * LD];
    __shared__ __align__(16) unsigned short Ks[64 * LD];
    __shared__ __align__(16) unsigned short Vs[64 * LD];  // rows d, cols s
    __shared__ __align__(16) unsigned short Ps[64 * LD];

    const int tid = threadIdx.x;
    const int wave = tid >> 6, lane = tid & 63;
    const int quad = lane >> 4, l16 = lane & 15;
    const int qb = blockIdx.x * 64;
    const int h = blockIdx.y, b = blockIdx.z;

    const unsigned short* Qg = qh + ((size_t)(b * NH + h) * T_SZ + qb) * HD;
    const unsigned short* Kg = kh + (size_t)(b * NH + h) * T_SZ * HD;
    const unsigned short* Vg = vt + (size_t)(b * NH + h) * HD * T_SZ;

    #pragma unroll
    for (int i = 0; i < 2; ++i) {
        int cch = tid + i * 256;
        int row = cch >> 3, col8 = (cch & 7) * 8;
        *(short8*)&Qs[row * LD + col8] = *(const short8*)&Qg[row * 64 + col8];
    }
    __syncthreads();

    short8 qf[2];
    qf[0] = *(const short8*)&Qs[(wave * 16 + l16) * LD + quad * 8];
    qf[1] = *(const short8*)&Qs[(wave * 16 + l16) * LD + 32 + quad * 8];

    float m_i[4], l_i[4];
    floatx4 o[4] = {};
    #pragma unroll
    for (int i = 0; i < 4; ++i) { m_i[i] = -1e30f; l_i[i] = 0.0f; }

    for (int st = 0; st < T_SZ; st += 64) {
        #pragma unroll
        for (int i = 0; i < 2; ++i) {
            int cch = tid + i * 256;
            int row = cch >> 3, col8 = (cch & 7) * 8;
            *(short8*)&Ks[row * LD + col8] =
                *(const short8*)&Kg[(size_t)(st + row) * 64 + col8];
            *(short8*)&Vs[row * LD + col8] =
                *(const short8*)&Vg[(size_t)row * T_SZ + st + col8];
        }
        __syncthreads();

        // S = q̂ K^T  (log2 units; scale folded into q̂)
        floatx4 sc[4];
        #pragma unroll
        for (int nt = 0; nt < 4; ++nt) {
            short8 kf0 = *(const short8*)&Ks[(nt * 16 + l16) * LD + quad * 8];
            short8 kf1 = *(const short8*)&Ks[(nt * 16 + l16) * LD + 32 + quad * 8];
            floatx4 zz = {0.f, 0.f, 0.f, 0.f};
            zz = __builtin_amdgcn_mfma_f32_16x16x32_bf16(qf[0], kf0, zz, 0, 0, 0);
            sc[nt] = __builtin_amdgcn_mfma_f32_16x16x32_bf16(qf[1], kf1, zz, 0, 0, 0);
        }

        // online softmax; row r = quad*4+i spread over 16 lanes (l16)
        #pragma unroll
        for (int i = 0; i < 4; ++i) {
            float mx = fmaxf(fmaxf(sc[0][i], sc[1][i]), fmaxf(sc[2][i], sc[3][i]));
            mx = fmaxf(mx, __shfl_xor(mx, 1, 64));
            mx = fmaxf(mx, __shfl_xor(mx, 2, 64));
            mx = fmaxf(mx, __shfl_xor(mx, 4, 64));
            mx = fmaxf(mx, __shfl_xor(mx, 8, 64));
            float mn = fmaxf(m_i[i], mx);
            float al = exp2f(m_i[i] - mn);
            float rs = 0.0f;
            #pragma unroll
            for (int nt = 0; nt < 4; ++nt) {
                float p = exp2f(sc[nt][i] - mn);
                sc[nt][i] = p;
                rs += p;
            }
            rs += __shfl_xor(rs, 1, 64);
            rs += __shfl_xor(rs, 2, 64);
            rs += __shfl_xor(rs, 4, 64);
            rs += __shfl_xor(rs, 8, 64);
            l_i[i] = l_i[i] * al + rs;
            m_i[i] = mn;
            #pragma unroll
            for (int nt = 0; nt < 4; ++nt) o[nt][i] *= al;
        }

        // P: C-layout regs -> LDS (wave-local rows)
        #pragma unroll
        for (int nt = 0; nt < 4; ++nt)
            #pragma unroll
            for (int i = 0; i < 4; ++i)
                Ps[(wave * 16 + quad * 4 + i) * LD + nt * 16 + l16] = f2bf(sc[nt][i]);
        __syncthreads();

        // O += P V
        #pragma unroll
        for (int cc = 0; cc < 2; ++cc) {
            short8 pf = *(const short8*)&Ps[(wave * 16 + l16) * LD + cc * 32 + quad * 8];
            #pragma unroll
            for (int nt = 0; nt < 4; ++nt) {
                short8 vf = *(const short8*)&Vs[(nt * 16 + l16) * LD + cc * 32 + quad * 8];
                o[nt] = __builtin_amdgcn_mfma_f32_16x16x32_bf16(pf, vf, o[nt], 0, 0, 0);
            }
        }
        __syncthreads();
    }

    // epilogue: y (B,T,C) bf16
    #pragma unroll
    for (int nt = 0; nt < 4; ++nt)
        #pragma unroll
        for (int i = 0; i < 4; ++i) {
            int row = qb + wave * 16 + quad * 4 + i;
            int col = h * 64 + nt * 16 + l16;
            y[((size_t)b * T_SZ + row) * C_SZ + col] = f2bf(o[nt][i] / l_i[i]);
        }
}

// ---------------------------------------------------------------------------
extern "C" void kernel_launch(void* const* d_in, const int* in_sizes, int n_in,
                              void* d_out, int out_size, void* d_ws, size_t ws_size,
                              hipStream_t stream)
{
    const float* x    = (const float*)d_in[0];
    const float* cosp = (const float*)d_in[1];
    const float* sinp = (const float*)d_in[2];
    const float* Wq   = (const float*)d_in[3];
    const float* Wk   = (const float*)d_in[4];
    const float* Wv   = (const float*)d_in[5];
    const float* Wo   = (const float*)d_in[6];
    float* out = (float*)d_out;

    // workspace: 4 bf16 buffers x 8 MB = 32 MB total
    char* ws = (char*)d_ws;
    unsigned short* qh = (unsigned short*)(ws);               // (B,H,T,D)
    unsigned short* kh = (unsigned short*)(ws + (8u  << 20)); // (B,H,T,D)
    unsigned short* vt = (unsigned short*)(ws + (16u << 20)); // (B,H,D,T)
    unsigned short* yb = (unsigned short*)(ws + (24u << 20)); // (B,T,C)

    // QKV projection + fused RoPE/RMSNorm/transpose epilogues
    gemm_nt<0><<<dim3(32, 8, 3), 256, 0, stream>>>(
        x, nullptr, Wq, Wk, Wv, cosp, sinp, qh, kh, vt, nullptr);
    // attention
    attn<<<dim3(32, NH, B_SZ), 256, 0, stream>>>(qh, kh, vt, yb);
    // output projection -> fp32 d_out
    gemm_nt<1><<<dim3(32, 8, 1), 256, 0, stream>>>(
        nullptr, yb, Wo, nullptr, nullptr, nullptr, nullptr,
        nullptr, nullptr, nullptr, out);
}

// Round 4
// 231.459 us; speedup vs baseline: 1.4688x; 1.4688x over previous
//
#include <hip/hip_runtime.h>
#include <stdint.h>

typedef __attribute__((ext_vector_type(8))) short short8;
typedef __attribute__((ext_vector_type(4))) float floatx4;
typedef __attribute__((ext_vector_type(4))) unsigned short ushort4v;

#define B_SZ 2
#define T_SZ 2048
#define NH   16
#define HD   64
#define C_SZ 1024
#define M_SZ (B_SZ * T_SZ)   // 4096 tokens

static __device__ __forceinline__ unsigned short f2bf(float f) {
    union { float f; unsigned int u; } v; v.f = f;
    unsigned int r = v.u + 0x7fffu + ((v.u >> 16) & 1u);
    return (unsigned short)(r >> 16);
}

// ---------------------------------------------------------------------------
// fp32 -> bf16 pre-convert (memory-bound): y=0 -> x (4096x1024), y=1..4 -> W's
// ---------------------------------------------------------------------------
__global__ __launch_bounds__(256)
void cvtk(const float* __restrict__ x,
          const float* __restrict__ w0, const float* __restrict__ w1,
          const float* __restrict__ w2, const float* __restrict__ w3,
          unsigned short* __restrict__ xb, unsigned short* __restrict__ wb)
{
    const float* src; unsigned short* dst; int n4;
    const int y = blockIdx.y;
    if (y == 0) { src = x; dst = xb; n4 = (M_SZ * C_SZ) / 4; }
    else {
        src = (y == 1 ? w0 : y == 2 ? w1 : y == 3 ? w2 : w3);
        dst = wb + (size_t)(y - 1) * C_SZ * C_SZ;
        n4 = (C_SZ * C_SZ) / 4;
    }
    for (int i = blockIdx.x * 256 + threadIdx.x; i < n4; i += gridDim.x * 256) {
        float4 f = *(const float4*)&src[(size_t)i * 4];
        ushort4v u;
        u.x = f2bf(f.x); u.y = f2bf(f.y); u.z = f2bf(f.z); u.w = f2bf(f.w);
        *(ushort4v*)&dst[(size_t)i * 4] = u;
    }
}

// ---------------------------------------------------------------------------
// NT GEMM, all-bf16 inputs: C[m,n] = sum_k A[m,k]*W[n,k]  (M=4096, N=K=1024)
// 128x128 tile, BK=32, 2x2 waves, 4x4 16x16x32 bf16 MFMAs per wave.
// MODE 0 (QKV): Wp = Wb + z*C*C; fused epilogues:
//   z=0: RoPE+RMSNorm+0.125*log2e -> qh (B,H,T,D) ; z=1: RoPE+RMSNorm -> kh
//   z=2: transpose -> vt (B,H,D,T)
// MODE 1 (out-proj): writes fp32 (B,T,C) to Cf.
// ---------------------------------------------------------------------------
template <int MODE>
__global__ __launch_bounds__(256)
void gemm_nt(const unsigned short* __restrict__ A,
             const unsigned short* __restrict__ Wb,
             const float* __restrict__ cosp,
             const float* __restrict__ sinp,
             unsigned short* __restrict__ qh,
             unsigned short* __restrict__ kh,
             unsigned short* __restrict__ vt,
             float* __restrict__ Cf)
{
    constexpr int K = C_SZ;
    constexpr int LDST = 40;  // 32 + 8 pad
    __shared__ __align__(16) unsigned short As[128 * LDST];
    __shared__ __align__(16) unsigned short Bs[128 * LDST];

    const int tid  = threadIdx.x;
    const int wave = tid >> 6, lane = tid & 63;
    const int wm = wave >> 1, wn = wave & 1;
    const int quad = lane >> 4, l16 = lane & 15;
    const int mb = blockIdx.x * 128, nb = blockIdx.y * 128;
    const int z  = blockIdx.z;

    const unsigned short* Wp = (MODE == 0) ? (Wb + (size_t)z * C_SZ * C_SZ) : Wb;

    floatx4 acc[4][4] = {};

    const int arow = tid >> 2;
    const int acol = (tid & 3) * 8;

    for (int k0 = 0; k0 < K; k0 += 32) {
        __syncthreads();
        #pragma unroll
        for (int i = 0; i < 2; ++i) {
            int row = arow + i * 64;
            *(short8*)&As[row * LDST + acol] =
                *(const short8*)&A[(size_t)(mb + row) * K + k0 + acol];
            *(short8*)&Bs[row * LDST + acol] =
                *(const short8*)&Wp[(size_t)(nb + row) * K + k0 + acol];
        }
        __syncthreads();

        short8 af[4], bfr[4];
        #pragma unroll
        for (int mt = 0; mt < 4; ++mt)
            af[mt] = *(const short8*)&As[(wm * 64 + mt * 16 + l16) * LDST + quad * 8];
        #pragma unroll
        for (int nt = 0; nt < 4; ++nt)
            bfr[nt] = *(const short8*)&Bs[(wn * 64 + nt * 16 + l16) * LDST + quad * 8];
        #pragma unroll
        for (int mt = 0; mt < 4; ++mt)
            #pragma unroll
            for (int nt = 0; nt < 4; ++nt)
                acc[mt][nt] = __builtin_amdgcn_mfma_f32_16x16x32_bf16(
                    af[mt], bfr[nt], acc[mt][nt], 0, 0, 0);
    }

    if (MODE == 1) {
        #pragma unroll
        for (int mt = 0; mt < 4; ++mt)
            #pragma unroll
            for (int nt = 0; nt < 4; ++nt)
                #pragma unroll
                for (int i = 0; i < 4; ++i) {
                    int row = mb + wm * 64 + mt * 16 + quad * 4 + i;
                    int col = nb + wn * 64 + nt * 16 + l16;
                    Cf[(size_t)row * C_SZ + col] = acc[mt][nt][i];
                }
        return;
    }

    const int h = blockIdx.y * 2 + wn;   // head (wave-uniform)

    if (z == 2) {
        #pragma unroll
        for (int mt = 0; mt < 4; ++mt) {
            int gr0 = mb + wm * 64 + mt * 16 + quad * 4;
            int b = gr0 >> 11, t0 = gr0 & (T_SZ - 1);
            #pragma unroll
            for (int nt = 0; nt < 4; ++nt) {
                int d = nt * 16 + l16;
                ushort4v pk;
                pk.x = f2bf(acc[mt][nt][0]);
                pk.y = f2bf(acc[mt][nt][1]);
                pk.z = f2bf(acc[mt][nt][2]);
                pk.w = f2bf(acc[mt][nt][3]);
                *(ushort4v*)&vt[((size_t)(b * NH + h) * HD + d) * T_SZ + t0] = pk;
            }
        }
        return;
    }

    unsigned short* dst = (z == 0) ? qh : kh;
    const float qscale = (z == 0) ? (0.125f * 1.4426950408889634f) : 1.0f;
    const float eps = 1.1920929e-07f;

    #pragma unroll
    for (int mt = 0; mt < 4; ++mt) {
        #pragma unroll
        for (int i = 0; i < 4; ++i) {
            int gr = mb + wm * 64 + mt * 16 + quad * 4 + i;
            int b = gr >> 11, t = gr & (T_SZ - 1);
            float ce = cosp[t * 32 + l16];
            float se = sinp[t * 32 + l16];
            float co = cosp[t * 32 + 16 + l16];
            float so = sinp[t * 32 + 16 + l16];
            float a0 = acc[mt][0][i], a1 = acc[mt][1][i];
            float a2 = acc[mt][2][i], a3 = acc[mt][3][i];
            float y0 = a0 * ce + a2 * se;
            float y1 = a1 * co + a3 * so;
            float y2 = a2 * ce - a0 * se;
            float y3 = a3 * co - a1 * so;
            float ss = y0 * y0 + y1 * y1 + y2 * y2 + y3 * y3;
            ss += __shfl_xor(ss, 1, 64);
            ss += __shfl_xor(ss, 2, 64);
            ss += __shfl_xor(ss, 4, 64);
            ss += __shfl_xor(ss, 8, 64);
            float rn = rsqrtf(ss * (1.0f / 64.0f) + eps) * qscale;
            size_t base = ((size_t)(b * NH + h) * T_SZ + t) * (size_t)HD;
            dst[base +  0 + l16] = f2bf(y0 * rn);
            dst[base + 16 + l16] = f2bf(y1 * rn);
            dst[base + 32 + l16] = f2bf(y2 * rn);
            dst[base + 48 + l16] = f2bf(y3 * rn);
        }
    }
}

// ---------------------------------------------------------------------------
// Flash attention, S^T formulation. Block = 128 queries of one (b,h),
// 4 waves arranged 2(key-half) x 2(q-half). Q frags live in registers.
// No max tracking: scores bounded by ±8/ln2 in log2 units (RMSNorm), so
// p = exp2(s) unnormalized; divide by l once at the end.
// S^T = K x Q^T (lane owns q col = l16); PV as O^T = V^T x P^T.
// ---------------------------------------------------------------------------
__global__ __launch_bounds__(256, 2)
void attn(const unsigned short* __restrict__ qh,
          const unsigned short* __restrict__ kh,
          const unsigned short* __restrict__ vt,
          unsigned short* __restrict__ yb)
{
    __shared__ __align__(16) char smem[36864];
    __shared__ float lred[2][128];

    unsigned short* Ks = (unsigned short*)smem;            // 64 x 72
    unsigned short* Vs = Ks + 64 * 72;                     // 64 x 72 (rows d, cols s)
    unsigned short* Psall = Vs + 64 * 72;                  // 4 waves x (64 x 36)
    float* Ored = (float*)smem;                            // epilogue reuse: 2 x 64 x 68

    const int tid = threadIdx.x;
    const int wave = tid >> 6, lane = tid & 63;
    const int wk = wave & 1, wq = wave >> 1;
    const int quad = lane >> 4, l16 = lane & 15;
    const int qb = blockIdx.x * 128;
    const int h = blockIdx.y, b = blockIdx.z;

    unsigned short* Ps = Psall + wave * (64 * 36);

    const unsigned short* Qg = qh + ((size_t)(b * NH + h) * T_SZ + qb) * HD;
    const unsigned short* Kg = kh + (size_t)(b * NH + h) * T_SZ * HD;
    const unsigned short* Vg = vt + (size_t)(b * NH + h) * HD * T_SZ;

    // Q B-frags in registers: q row = wq*64 + n*16 + l16, d = c*32 + quad*8..+7
    short8 qfr[4][2];
    #pragma unroll
    for (int n = 0; n < 4; ++n)
        #pragma unroll
        for (int c = 0; c < 2; ++c)
            qfr[n][c] = *(const short8*)&Qg[(size_t)(wq * 64 + n * 16 + l16) * HD + c * 32 + quad * 8];

    floatx4 o[4][4] = {};          // [nd (d tile)][nv (q tile)]
    float l_acc[4] = {0.f, 0.f, 0.f, 0.f};

    const int srow = tid >> 2;          // 0..63
    const int scol = (tid & 3) * 8;     // 0,8,16,24

    for (int st = 0; st < T_SZ; st += 64) {
        short8 k0 = *(const short8*)&Kg[(size_t)(st + srow) * HD + scol];
        short8 k1 = *(const short8*)&Kg[(size_t)(st + srow) * HD + scol + 32];
        short8 v0 = *(const short8*)&Vg[(size_t)srow * T_SZ + st + scol];
        short8 v1 = *(const short8*)&Vg[(size_t)srow * T_SZ + st + scol + 32];
        *(short8*)&Ks[srow * 72 + scol]      = k0;
        *(short8*)&Ks[srow * 72 + scol + 32] = k1;
        *(short8*)&Vs[srow * 72 + scol]      = v0;
        *(short8*)&Vs[srow * 72 + scol + 32] = v1;
        __syncthreads();

        // S^T tiles: A = K rows (m=key), B = Q (n=q); D col=l16=q, row=key
        floatx4 s[2][4];
        #pragma unroll
        for (int mt = 0; mt < 2; ++mt) {
            const int kr = (wk * 32 + mt * 16 + l16) * 72;
            short8 af0 = *(const short8*)&Ks[kr + quad * 8];
            short8 af1 = *(const short8*)&Ks[kr + 32 + quad * 8];
            #pragma unroll
            for (int n = 0; n < 4; ++n) {
                floatx4 zz = {0.f, 0.f, 0.f, 0.f};
                zz = __builtin_amdgcn_mfma_f32_16x16x32_bf16(af0, qfr[n][0], zz, 0, 0, 0);
                s[mt][n] = __builtin_amdgcn_mfma_f32_16x16x32_bf16(af1, qfr[n][1], zz, 0, 0, 0);
            }
        }

        // p = exp2(s); accumulate l per-lane; pack to bf16 pairs; wave-private Ps
        #pragma unroll
        for (int mt = 0; mt < 2; ++mt)
            #pragma unroll
            for (int n = 0; n < 4; ++n) {
                float p0 = exp2f(s[mt][n][0]);
                float p1 = exp2f(s[mt][n][1]);
                float p2 = exp2f(s[mt][n][2]);
                float p3 = exp2f(s[mt][n][3]);
                l_acc[n] += (p0 + p1) + (p2 + p3);
                uint2 pk;
                pk.x = (unsigned int)f2bf(p0) | ((unsigned int)f2bf(p1) << 16);
                pk.y = (unsigned int)f2bf(p2) | ((unsigned int)f2bf(p3) << 16);
                *(uint2*)&Ps[(n * 16 + l16) * 36 + mt * 16 + quad * 4] = pk;
            }

        // O^T += V^T x P^T  (A = Vs rows d over this wave's 32 keys)
        short8 av[4];
        #pragma unroll
        for (int nd = 0; nd < 4; ++nd)
            av[nd] = *(const short8*)&Vs[(nd * 16 + l16) * 72 + wk * 32 + quad * 8];
        #pragma unroll
        for (int nv = 0; nv < 4; ++nv) {
            union { short8 v; uint2 d[2]; } pf;
            pf.d[0] = *(const uint2*)&Ps[(nv * 16 + l16) * 36 + quad * 8];
            pf.d[1] = *(const uint2*)&Ps[(nv * 16 + l16) * 36 + quad * 8 + 4];
            #pragma unroll
            for (int nd = 0; nd < 4; ++nd)
                o[nd][nv] = __builtin_amdgcn_mfma_f32_16x16x32_bf16(av[nd], pf.v, o[nd][nv], 0, 0, 0);
        }
        __syncthreads();
    }

    // reduce l across quads (same l16 holds same q)
    #pragma unroll
    for (int n = 0; n < 4; ++n) {
        l_acc[n] += __shfl_xor(l_acc[n], 16, 64);
        l_acc[n] += __shfl_xor(l_acc[n], 32, 64);
    }
    if (quad == 0) {
        #pragma unroll
        for (int n = 0; n < 4; ++n)
            lred[wk][wq * 64 + n * 16 + l16] = l_acc[n];
    }
    __syncthreads();

    // cross-wave (wk) O reduction through reused LDS
    if (wk == 1) {
        #pragma unroll
        for (int nv = 0; nv < 4; ++nv)
            #pragma unroll
            for (int nd = 0; nd < 4; ++nd)
                *(floatx4*)&Ored[(size_t)wq * (64 * 68) + (nv * 16 + l16) * 68 + nd * 16 + quad * 4] = o[nd][nv];
    }
    __syncthreads();

    if (wk == 0) {
        #pragma unroll
        for (int nv = 0; nv < 4; ++nv) {
            float lt = lred[0][wq * 64 + nv * 16 + l16] + lred[1][wq * 64 + nv * 16 + l16];
            float inv = 1.0f / lt;
            int t = qb + wq * 64 + nv * 16 + l16;
            #pragma unroll
            for (int nd = 0; nd < 4; ++nd) {
                floatx4 r = *(const floatx4*)&Ored[(size_t)wq * (64 * 68) + (nv * 16 + l16) * 68 + nd * 16 + quad * 4];
                floatx4 ov = o[nd][nv];
                ushort4v u;
                u.x = f2bf((ov[0] + r[0]) * inv);
                u.y = f2bf((ov[1] + r[1]) * inv);
                u.z = f2bf((ov[2] + r[2]) * inv);
                u.w = f2bf((ov[3] + r[3]) * inv);
                *(ushort4v*)&yb[((size_t)b * T_SZ + t) * C_SZ + h * 64 + nd * 16 + quad * 4] = u;
            }
        }
    }
}

// ---------------------------------------------------------------------------
extern "C" void kernel_launch(void* const* d_in, const int* in_sizes, int n_in,
                              void* d_out, int out_size, void* d_ws, size_t ws_size,
                              hipStream_t stream)
{
    const float* x    = (const float*)d_in[0];
    const float* cosp = (const float*)d_in[1];
    const float* sinp = (const float*)d_in[2];
    const float* Wq   = (const float*)d_in[3];
    const float* Wk   = (const float*)d_in[4];
    const float* Wv   = (const float*)d_in[5];
    const float* Wo   = (const float*)d_in[6];
    float* out = (float*)d_out;

    // workspace (40 MB): xb/yb alias (xb dead after QKV GEMM)
    char* ws = (char*)d_ws;
    unsigned short* xb = (unsigned short*)(ws);               // 8 MB (B,T,C) bf16
    unsigned short* yb = xb;                                  // alias, used after attn
    unsigned short* wb = (unsigned short*)(ws + (8u  << 20)); // 8 MB: Wq,Wk,Wv,Wo bf16
    unsigned short* qh = (unsigned short*)(ws + (16u << 20)); // 8 MB (B,H,T,D)
    unsigned short* kh = (unsigned short*)(ws + (24u << 20)); // 8 MB (B,H,T,D)
    unsigned short* vt = (unsigned short*)(ws + (32u << 20)); // 8 MB (B,H,D,T)

    cvtk<<<dim3(512, 5), 256, 0, stream>>>(x, Wq, Wk, Wv, Wo, xb, wb);
    gemm_nt<0><<<dim3(32, 8, 3), 256, 0, stream>>>(
        xb, wb, cosp, sinp, qh, kh, vt, nullptr);
    attn<<<dim3(16, NH, B_SZ), 256, 0, stream>>>(qh, kh, vt, yb);
    gemm_nt<1><<<dim3(32, 8, 1), 256, 0, stream>>>(
        yb, wb + (size_t)3 * C_SZ * C_SZ, nullptr, nullptr,
        nullptr, nullptr, nullptr, out);
}

// Round 5
// 216.304 us; speedup vs baseline: 1.5717x; 1.0701x over previous
//
#include <hip/hip_runtime.h>
#include <stdint.h>

typedef __attribute__((ext_vector_type(8))) short short8;
typedef __attribute__((ext_vector_type(4))) float floatx4;

#define B_SZ 2
#define T_SZ 2048
#define NH   16
#define HD   64
#define C_SZ 1024
#define M_SZ (B_SZ * T_SZ)   // 4096 tokens

// packed fp32x2 -> bf16x2 (RNE), gfx950 hardware instruction
static __device__ __forceinline__ unsigned int cvt2(float a, float b) {
    unsigned int r;
    asm("v_cvt_pk_bf16_f32 %0, %1, %2" : "=v"(r) : "v"(a), "v"(b));
    return r;
}
static __device__ __forceinline__ unsigned short f2bf(float a) {
    return (unsigned short)(cvt2(a, 0.0f) & 0xffffu);
}

// async global->LDS, 16B per lane; LDS dest = wave-uniform base + lane*16
static __device__ __forceinline__ void gload_lds16(const void* g, void* l) {
    __builtin_amdgcn_global_load_lds(
        (const __attribute__((address_space(1))) void*)g,
        (__attribute__((address_space(3))) void*)l, 16, 0, 0);
}

// ---------------------------------------------------------------------------
// fp32 -> bf16 pre-convert (memory-bound): y=0 -> x, y=1..4 -> W's
// ---------------------------------------------------------------------------
__global__ __launch_bounds__(256)
void cvtk(const float* __restrict__ x,
          const float* __restrict__ w0, const float* __restrict__ w1,
          const float* __restrict__ w2, const float* __restrict__ w3,
          unsigned short* __restrict__ xb, unsigned short* __restrict__ wb)
{
    const float* src; unsigned short* dst; int n4;
    const int y = blockIdx.y;
    if (y == 0) { src = x; dst = xb; n4 = (M_SZ * C_SZ) / 4; }
    else {
        src = (y == 1 ? w0 : y == 2 ? w1 : y == 3 ? w2 : w3);
        dst = wb + (size_t)(y - 1) * C_SZ * C_SZ;
        n4 = (C_SZ * C_SZ) / 4;
    }
    for (int i = blockIdx.x * 256 + threadIdx.x; i < n4; i += gridDim.x * 256) {
        float4 f = *(const float4*)&src[(size_t)i * 4];
        uint2 u;
        u.x = cvt2(f.x, f.y);
        u.y = cvt2(f.z, f.w);
        *(uint2*)&dst[(size_t)i * 4] = u;
    }
}

// ---------------------------------------------------------------------------
// NT GEMM, all-bf16: C[m,n] = sum_k A[m,k]*W[n,k]  (M=4096, N=K=1024)
// 128x128 tile, BK=32, 2x2 waves, 4x4 16x16x32 bf16 MFMAs/wave.
// Staging via global_load_lds (16B/lane) into XOR-swizzled unpadded LDS:
//   LDS[r][cslot] holds global col chunk (cslot ^ ((r>>1)&3)); frag reads
//   use chunk (quad ^ ((r>>1)&3)) -> 2-way banks max (free).
// MODE 0 (QKV): Wp = Wb + z*C*C; fused epilogues (z=0 q / z=1 k / z=2 v).
// MODE 1 (out-proj): writes fp32 (B,T,C) to Cf.
// ---------------------------------------------------------------------------
template <int MODE>
__global__ __launch_bounds__(256)
void gemm_nt(const unsigned short* __restrict__ A,
             const unsigned short* __restrict__ Wb,
             const float* __restrict__ cosp,
             const float* __restrict__ sinp,
             unsigned short* __restrict__ qh,
             unsigned short* __restrict__ kh,
             unsigned short* __restrict__ vt,
             float* __restrict__ Cf)
{
    constexpr int K = C_SZ;
    __shared__ __align__(16) unsigned short As[128 * 32];
    __shared__ __align__(16) unsigned short Bs[128 * 32];

    const int tid  = threadIdx.x;
    const int wave = tid >> 6, lane = tid & 63;
    const int wm = wave >> 1, wn = wave & 1;
    const int quad = lane >> 4, l16 = lane & 15;
    const int mb = blockIdx.x * 128, nb = blockIdx.y * 128;
    const int z  = blockIdx.z;

    const unsigned short* Wp = (MODE == 0) ? (Wb + (size_t)z * C_SZ * C_SZ) : Wb;

    floatx4 acc[4][4] = {};

    const int lrow = lane >> 2;        // 0..15 within 16-row chunk
    const int lsw  = lane & 3;         // col slot before swizzle

    for (int k0 = 0; k0 < K; k0 += 32) {
        __syncthreads();   // previous tile fully consumed
        #pragma unroll
        for (int c = 0; c < 2; ++c) {
            int r = (wave * 2 + c) * 16 + lrow;             // 0..127
            int col = ((lsw ^ ((r >> 1) & 3))) * 8;         // swizzled source col
            gload_lds16(&A[(size_t)(mb + r) * K + k0 + col], &As[(wave * 2 + c) * 512]);
            gload_lds16(&Wp[(size_t)(nb + r) * K + k0 + col], &Bs[(wave * 2 + c) * 512]);
        }
        __syncthreads();   // async loads drained (vmcnt before barrier)

        short8 af[4], bfr[4];
        #pragma unroll
        for (int mt = 0; mt < 4; ++mt) {
            int r = wm * 64 + mt * 16 + l16;
            af[mt] = *(const short8*)&As[r * 32 + ((quad ^ ((r >> 1) & 3)) * 8)];
        }
        #pragma unroll
        for (int nt = 0; nt < 4; ++nt) {
            int r = wn * 64 + nt * 16 + l16;
            bfr[nt] = *(const short8*)&Bs[r * 32 + ((quad ^ ((r >> 1) & 3)) * 8)];
        }
        #pragma unroll
        for (int mt = 0; mt < 4; ++mt)
            #pragma unroll
            for (int nt = 0; nt < 4; ++nt)
                acc[mt][nt] = __builtin_amdgcn_mfma_f32_16x16x32_bf16(
                    af[mt], bfr[nt], acc[mt][nt], 0, 0, 0);
    }

    if (MODE == 1) {
        #pragma unroll
        for (int mt = 0; mt < 4; ++mt)
            #pragma unroll
            for (int nt = 0; nt < 4; ++nt)
                #pragma unroll
                for (int i = 0; i < 4; ++i) {
                    int row = mb + wm * 64 + mt * 16 + quad * 4 + i;
                    int col = nb + wn * 64 + nt * 16 + l16;
                    Cf[(size_t)row * C_SZ + col] = acc[mt][nt][i];
                }
        return;
    }

    const int h = blockIdx.y * 2 + wn;   // head (wave-uniform)

    if (z == 2) {
        // V transpose-scatter to vt (B,H,D,T); 4 consecutive t per 8B store
        #pragma unroll
        for (int mt = 0; mt < 4; ++mt) {
            int gr0 = mb + wm * 64 + mt * 16 + quad * 4;
            int b = gr0 >> 11, t0 = gr0 & (T_SZ - 1);
            #pragma unroll
            for (int nt = 0; nt < 4; ++nt) {
                int d = nt * 16 + l16;
                uint2 pk;
                pk.x = cvt2(acc[mt][nt][0], acc[mt][nt][1]);
                pk.y = cvt2(acc[mt][nt][2], acc[mt][nt][3]);
                *(uint2*)&vt[((size_t)(b * NH + h) * HD + d) * T_SZ + t0] = pk;
            }
        }
        return;
    }

    unsigned short* dst = (z == 0) ? qh : kh;
    const float qscale = (z == 0) ? (0.125f * 1.4426950408889634f) : 1.0f;
    const float eps = 1.1920929e-07f;

    #pragma unroll
    for (int mt = 0; mt < 4; ++mt) {
        #pragma unroll
        for (int i = 0; i < 4; ++i) {
            int gr = mb + wm * 64 + mt * 16 + quad * 4 + i;
            int b = gr >> 11, t = gr & (T_SZ - 1);
            float ce = cosp[t * 32 + l16];
            float se = sinp[t * 32 + l16];
            float co = cosp[t * 32 + 16 + l16];
            float so = sinp[t * 32 + 16 + l16];
            float a0 = acc[mt][0][i], a1 = acc[mt][1][i];
            float a2 = acc[mt][2][i], a3 = acc[mt][3][i];
            float y0 = a0 * ce + a2 * se;
            float y1 = a1 * co + a3 * so;
            float y2 = a2 * ce - a0 * se;
            float y3 = a3 * co - a1 * so;
            float ss = y0 * y0 + y1 * y1 + y2 * y2 + y3 * y3;
            ss += __shfl_xor(ss, 1, 64);
            ss += __shfl_xor(ss, 2, 64);
            ss += __shfl_xor(ss, 4, 64);
            ss += __shfl_xor(ss, 8, 64);
            float rn = rsqrtf(ss * (1.0f / 64.0f) + eps) * qscale;
            size_t base = ((size_t)(b * NH + h) * T_SZ + t) * (size_t)HD;
            dst[base +  0 + l16] = f2bf(y0 * rn);
            dst[base + 16 + l16] = f2bf(y1 * rn);
            dst[base + 32 + l16] = f2bf(y2 * rn);
            dst[base + 48 + l16] = f2bf(y3 * rn);
        }
    }
}

// ---------------------------------------------------------------------------
// Flash attention, S^T formulation. Block = 512 threads = 8 waves
// (2 key-halves x 4 q-quarters) on a 128-query tile of one (b,h).
// Q frags in registers. No max tracking (RMSNorm bounds |s| <= ~11.6 in
// log2 units): p = exp2(s) unnormalized, divide by l at the end.
// ---------------------------------------------------------------------------
__global__ __launch_bounds__(512, 4)
void attn(const unsigned short* __restrict__ qh,
          const unsigned short* __restrict__ kh,
          const unsigned short* __restrict__ vt,
          unsigned short* __restrict__ yb)
{
    __shared__ __align__(16) char smem[36864];
    __shared__ float lred[2][128];

    unsigned short* Ks = (unsigned short*)smem;            // 64 x 72
    unsigned short* Vs = Ks + 64 * 72;                     // 64 x 72 (rows d)
    unsigned short* Psall = Vs + 64 * 72;                  // 8 waves x 32 x 36
    float* Ored = (float*)smem;                            // reuse: 4 x 32 x 68

    const int tid = threadIdx.x;
    const int wave = tid >> 6, lane = tid & 63;
    const int wk = wave & 1, wq = wave >> 1;               // wq 0..3
    const int quad = lane >> 4, l16 = lane & 15;
    const int qb = blockIdx.x * 128;
    const int h = blockIdx.y, b = blockIdx.z;

    unsigned short* Ps = Psall + wave * (32 * 36);

    const unsigned short* Qg = qh + ((size_t)(b * NH + h) * T_SZ + qb) * HD;
    const unsigned short* Kg = kh + (size_t)(b * NH + h) * T_SZ * HD;
    const unsigned short* Vg = vt + (size_t)(b * NH + h) * HD * T_SZ;

    // Q B-frags: q row = wq*32 + n*16 + l16, d = c*32 + quad*8..+7
    short8 qfr[2][2];
    #pragma unroll
    for (int n = 0; n < 2; ++n)
        #pragma unroll
        for (int c = 0; c < 2; ++c)
            qfr[n][c] = *(const short8*)&Qg[(size_t)(wq * 32 + n * 16 + l16) * HD + c * 32 + quad * 8];

    floatx4 o[4][2] = {};          // [nd (d tile)][nv (q tile)]
    float l_acc[2] = {0.f, 0.f};

    const int srow = tid >> 3;          // 0..63
    const int scol = (tid & 7) * 8;     // 0,8,..,56

    for (int st = 0; st < T_SZ; st += 64) {
        short8 kv = *(const short8*)&Kg[(size_t)(st + srow) * HD + scol];
        short8 vv = *(const short8*)&Vg[(size_t)srow * T_SZ + st + scol];
        *(short8*)&Ks[srow * 72 + scol] = kv;
        *(short8*)&Vs[srow * 72 + scol] = vv;
        __syncthreads();

        // S^T: A = K rows (m = key), B = Q regs (n = q). D: col=l16=q, row=key
        floatx4 s[2][2];
        #pragma unroll
        for (int kt = 0; kt < 2; ++kt) {
            const int kr = (wk * 32 + kt * 16 + l16) * 72;
            short8 af0 = *(const short8*)&Ks[kr + quad * 8];
            short8 af1 = *(const short8*)&Ks[kr + 32 + quad * 8];
            #pragma unroll
            for (int n = 0; n < 2; ++n) {
                floatx4 zz = {0.f, 0.f, 0.f, 0.f};
                zz = __builtin_amdgcn_mfma_f32_16x16x32_bf16(af0, qfr[n][0], zz, 0, 0, 0);
                s[kt][n] = __builtin_amdgcn_mfma_f32_16x16x32_bf16(af1, qfr[n][1], zz, 0, 0, 0);
            }
        }

        // p = exp2(s); per-lane l accum; packed cvt; wave-private Ps
        #pragma unroll
        for (int kt = 0; kt < 2; ++kt)
            #pragma unroll
            for (int n = 0; n < 2; ++n) {
                float p0 = exp2f(s[kt][n][0]);
                float p1 = exp2f(s[kt][n][1]);
                float p2 = exp2f(s[kt][n][2]);
                float p3 = exp2f(s[kt][n][3]);
                l_acc[n] += (p0 + p1) + (p2 + p3);
                uint2 pk;
                pk.x = cvt2(p0, p1);
                pk.y = cvt2(p2, p3);
                *(uint2*)&Ps[(n * 16 + l16) * 36 + kt * 16 + quad * 4] = pk;
            }

        // O^T += V^T x P^T  (A = Vs rows d, k = this wave's 32 keys)
        short8 av[4];
        #pragma unroll
        for (int nd = 0; nd < 4; ++nd)
            av[nd] = *(const short8*)&Vs[(nd * 16 + l16) * 72 + wk * 32 + quad * 8];
        #pragma unroll
        for (int nv = 0; nv < 2; ++nv) {
            union { short8 v; uint2 d[2]; } pf;
            pf.d[0] = *(const uint2*)&Ps[(nv * 16 + l16) * 36 + quad * 8];
            pf.d[1] = *(const uint2*)&Ps[(nv * 16 + l16) * 36 + quad * 8 + 4];
            #pragma unroll
            for (int nd = 0; nd < 4; ++nd)
                o[nd][nv] = __builtin_amdgcn_mfma_f32_16x16x32_bf16(av[nd], pf.v, o[nd][nv], 0, 0, 0);
        }
        __syncthreads();
    }

    // l: reduce across quads (same l16 = same q)
    #pragma unroll
    for (int n = 0; n < 2; ++n) {
        l_acc[n] += __shfl_xor(l_acc[n], 16, 64);
        l_acc[n] += __shfl_xor(l_acc[n], 32, 64);
    }
    if (quad == 0) {
        #pragma unroll
        for (int n = 0; n < 2; ++n)
            lred[wk][wq * 32 + n * 16 + l16] = l_acc[n];
    }
    // cross-wave (wk) O reduction through reused LDS
    if (wk == 1) {
        #pragma unroll
        for (int nv = 0; nv < 2; ++nv)
            #pragma unroll
            for (int nd = 0; nd < 4; ++nd)
                *(floatx4*)&Ored[(size_t)wq * (32 * 68) + (nv * 16 + l16) * 68 + nd * 16 + quad * 4] = o[nd][nv];
    }
    __syncthreads();

    if (wk == 0) {
        #pragma unroll
        for (int nv = 0; nv < 2; ++nv) {
            int qi = wq * 32 + nv * 16 + l16;
            float lt = lred[0][qi] + lred[1][qi];
            float inv = 1.0f / lt;
            int t = qb + qi;
            #pragma unroll
            for (int nd = 0; nd < 4; ++nd) {
                floatx4 r = *(const floatx4*)&Ored[(size_t)wq * (32 * 68) + (nv * 16 + l16) * 68 + nd * 16 + quad * 4];
                floatx4 ov = o[nd][nv];
                uint2 u;
                u.x = cvt2((ov[0] + r[0]) * inv, (ov[1] + r[1]) * inv);
                u.y = cvt2((ov[2] + r[2]) * inv, (ov[3] + r[3]) * inv);
                *(uint2*)&yb[((size_t)b * T_SZ + t) * C_SZ + h * 64 + nd * 16 + quad * 4] = u;
            }
        }
    }
}

// ---------------------------------------------------------------------------
extern "C" void kernel_launch(void* const* d_in, const int* in_sizes, int n_in,
                              void* d_out, int out_size, void* d_ws, size_t ws_size,
                              hipStream_t stream)
{
    const float* x    = (const float*)d_in[0];
    const float* cosp = (const float*)d_in[1];
    const float* sinp = (const float*)d_in[2];
    const float* Wq   = (const float*)d_in[3];
    const float* Wk   = (const float*)d_in[4];
    const float* Wv   = (const float*)d_in[5];
    const float* Wo   = (const float*)d_in[6];
    float* out = (float*)d_out;

    // workspace (40 MB): xb/yb alias (xb dead after QKV GEMM)
    char* ws = (char*)d_ws;
    unsigned short* xb = (unsigned short*)(ws);               // 8 MB (B,T,C)
    unsigned short* yb = xb;                                  // alias after attn
    unsigned short* wb = (unsigned short*)(ws + (8u  << 20)); // 8 MB Wq,Wk,Wv,Wo
    unsigned short* qh = (unsigned short*)(ws + (16u << 20)); // 8 MB (B,H,T,D)
    unsigned short* kh = (unsigned short*)(ws + (24u << 20)); // 8 MB (B,H,T,D)
    unsigned short* vt = (unsigned short*)(ws + (32u << 20)); // 8 MB (B,H,D,T)

    cvtk<<<dim3(512, 5), 256, 0, stream>>>(x, Wq, Wk, Wv, Wo, xb, wb);
    gemm_nt<0><<<dim3(32, 8, 3), 256, 0, stream>>>(
        xb, wb, cosp, sinp, qh, kh, vt, nullptr);
    attn<<<dim3(16, NH, B_SZ), 512, 0, stream>>>(qh, kh, vt, yb);
    gemm_nt<1><<<dim3(32, 8, 1), 256, 0, stream>>>(
        yb, wb + (size_t)3 * C_SZ * C_SZ, nullptr, nullptr,
        nullptr, nullptr, nullptr, out);
}